// Round 21
// baseline (510.673 us; speedup 1.0000x reference)
//
#include <hip/hip_runtime.h>
#include <math.h>

#define NB_TOK 16384
#define DM     1024
#define NEXP   8
#define KIN    1536
#define SECBIT 0x40000000
#define TOKMSK 0x3FFFFFFF

typedef __attribute__((ext_vector_type(8))) short          short8;
typedef __attribute__((ext_vector_type(8))) unsigned short ushort8;
typedef __attribute__((ext_vector_type(4))) unsigned short ushort4v;
typedef __attribute__((ext_vector_type(8))) _Float16       half8;
typedef __attribute__((ext_vector_type(4))) float          floatx4;

#define AS1U(p) ((const __attribute__((address_space(1))) unsigned int*)(p))
#define AS3U(p) ((__attribute__((address_space(3))) unsigned int*)(p))

// fast gelu: A&S 7.1.26 erf approx, |err| <= 1.5e-7. ~14 VALU ops + one hw v_exp.
__device__ __forceinline__ float gelu_f(float x) {
    const float ax = fabsf(x) * 0.70710678118654752440f;
    const float t  = 1.0f / fmaf(0.3275911f, ax, 1.0f);
    float p = fmaf(t, 1.061405429f, -1.453152027f);
    p = fmaf(t, p, 1.421413741f);
    p = fmaf(t, p, -0.284496736f);
    p = fmaf(t, p, 0.254829592f);
    p = p * t;
    const float e = __expf(-ax * ax);
    float erf = fmaf(-p, e, 1.0f);
    erf = copysignf(erf, x);
    return 0.5f * x * (1.0f + erf);
}

__device__ __forceinline__ unsigned short f2bf(float x) {
    unsigned u = __float_as_uint(x);
    u = (u + 0x7FFF + ((u >> 16) & 1)) >> 16;   // RNE
    return (unsigned short)u;
}

__device__ __forceinline__ void split_h16(float x, unsigned short& hi, unsigned short& lo) {
    _Float16 h = (_Float16)x;
    float r = x - (float)h;
    _Float16 l = (_Float16)r;
    hi = *(unsigned short*)&h;
    lo = *(unsigned short*)&l;
}

// ---------------- feature split: concat fp32 -> fp16 hi/lo [tok][KIN], A scaled x4 ----------------
__global__ __launch_bounds__(256) void k_splitA(
    const float* __restrict__ f0, const float* __restrict__ f1,
    const float* __restrict__ f2, unsigned short* __restrict__ Ah,
    unsigned short* __restrict__ Al)
{
    const int i4  = blockIdx.x * 256 + threadIdx.x;
    const int tok = i4 / (KIN / 4);
    const int k   = (i4 % (KIN / 4)) * 4;
    const float* src; int ld, c;
    if (k < 768)       { src = f0; ld = 768; c = k; }
    else if (k < 1280) { src = f1; ld = 512; c = k - 768; }
    else               { src = f2; ld = 256; c = k - 1280; }
    const float4 v = *(const float4*)(src + (size_t)tok * ld + c);
    const float* vp = (const float*)&v;
    ushort4v hi, lo;
#pragma unroll
    for (int j = 0; j < 4; ++j) {
        unsigned short h, l;
        split_h16(vp[j] * 4.0f, h, l);
        hi[j] = h; lo[j] = l;
    }
    *(ushort4v*)(Ah + (size_t)tok * KIN + k) = hi;
    *(ushort4v*)(Al + (size_t)tok * KIN + k) = lo;
}

// ---------------- Ws fp32 [k][n] -> fp16 hi/lo transposed [n][k], scaled x256 ----------------
__global__ __launch_bounds__(256) void k_splitB(
    const float* __restrict__ Ws, unsigned short* __restrict__ BhT,
    unsigned short* __restrict__ BlT)
{
    __shared__ float s[32][33];
    const int n0 = blockIdx.x * 32, k0 = blockIdx.y * 32;
    const int c  = threadIdx.x & 31, r = threadIdx.x >> 5;
#pragma unroll
    for (int p = 0; p < 4; ++p)
        s[r + p * 8][c] = Ws[(size_t)(k0 + r + p * 8) * DM + n0 + c];
    __syncthreads();
#pragma unroll
    for (int p = 0; p < 4; ++p) {
        const int n = r + p * 8;
        unsigned short h, l;
        split_h16(s[c][n] * 256.0f, h, l);
        BhT[(size_t)(n0 + n) * KIN + k0 + c] = h;
        BlT[(size_t)(n0 + n) * KIN + k0 + c] = l;
    }
}

// ---------------- shared GEMM: fp16x2-split MFMA, BK=32, 32KB LDS -> 4 blocks/CU ----------------
// BK 64->32 keeps per-wave tile (64x32, acc[4][2]) and MFMA order bit-identical;
// LDS halves -> all 1024 blocks co-resident (32 waves/CU) so barrier drains overlap.
__global__ __launch_bounds__(512, 8) void k_shared_mfma(
    const unsigned short* __restrict__ Ah, const unsigned short* __restrict__ Al,
    const unsigned short* __restrict__ BhT, const unsigned short* __restrict__ BlT,
    const float* __restrict__ bs, float* __restrict__ h)
{
    __shared__ unsigned short ldsAh[128][32];   // 8KB each, 32KB total
    __shared__ unsigned short ldsAl[128][32];
    __shared__ unsigned short ldsBh[128][32];
    __shared__ unsigned short ldsBl[128][32];

    const int t    = threadIdx.x;          // 0..511
    const int lane = t & 63;
    const int wave = t >> 6;               // 0..7
    const int bid  = blockIdx.x;
    const int brow = ((bid >> 6) << 3) + (bid & 7);   // 0..127
    const int bcol = (bid >> 3) & 7;                  // 0..7
    const int row0 = brow * 128;
    const int n0g  = bcol * 128;

    // staging: 8KB/buffer = 512 threads x 16B; thread t -> row t>>2, chunk-slot t&3.
    // slot p holds logical chunk p ^ (row&3)  (4-slot XOR swizzle)
    const int srow = t >> 2;               // 0..127
    const int g    = (t & 3) ^ (srow & 3); // source logical chunk
    const unsigned short* sAh = Ah  + (size_t)(row0 + srow) * KIN + g * 8;
    const unsigned short* sAl = Al  + (size_t)(row0 + srow) * KIN + g * 8;
    const unsigned short* sBh = BhT + (size_t)(n0g + srow) * KIN + g * 8;
    const unsigned short* sBl = BlT + (size_t)(n0g + srow) * KIN + g * 8;

    // wave sub-tile: 64 rows (wr) x 32 cols (wc); acc[4][2]
    const int grp = lane >> 4;             // logical chunk for this lane's fragment
    const int wr = wave >> 2, wc = wave & 3;
    int offA[4], offB[2];
#pragma unroll
    for (int m = 0; m < 4; ++m) {
        const int rA = wr * 64 + m * 16 + (lane & 15);
        offA[m] = rA * 64 + (((grp ^ (rA & 3)) & 3) << 4);
    }
#pragma unroll
    for (int n = 0; n < 2; ++n) {
        const int rB = wc * 32 + n * 16 + (lane & 15);
        offB[n] = rB * 64 + (((grp ^ (rB & 3)) & 3) << 4);
    }

    floatx4 acc[4][2];
#pragma unroll
    for (int m = 0; m < 4; ++m)
#pragma unroll
        for (int n = 0; n < 2; ++n) acc[m][n] = (floatx4){0.f, 0.f, 0.f, 0.f};

    const char* lAh = (const char*)&ldsAh[0][0];
    const char* lAl = (const char*)&ldsAl[0][0];
    const char* lBh = (const char*)&ldsBh[0][0];
    const char* lBl = (const char*)&ldsBl[0][0];

    for (int kt = 0; kt < KIN / 32; ++kt) {
        const int k0 = kt * 32;
        __syncthreads();
        {
            const int dst = t * 16;
            __builtin_amdgcn_global_load_lds(AS1U(sAh + k0), AS3U((char*)lAh + dst), 16, 0, 0);
            __builtin_amdgcn_global_load_lds(AS1U(sAl + k0), AS3U((char*)lAl + dst), 16, 0, 0);
            __builtin_amdgcn_global_load_lds(AS1U(sBh + k0), AS3U((char*)lBh + dst), 16, 0, 0);
            __builtin_amdgcn_global_load_lds(AS1U(sBl + k0), AS3U((char*)lBl + dst), 16, 0, 0);
        }
        __syncthreads();
        half8 ah[4], al[4], bh[2], bl[2];
#pragma unroll
        for (int m = 0; m < 4; ++m) {
            ah[m] = *(const half8*)(lAh + offA[m]);
            al[m] = *(const half8*)(lAl + offA[m]);
        }
#pragma unroll
        for (int n = 0; n < 2; ++n) {
            bh[n] = *(const half8*)(lBh + offB[n]);
            bl[n] = *(const half8*)(lBl + offB[n]);
        }
#pragma unroll
        for (int m = 0; m < 4; ++m)
#pragma unroll
            for (int n = 0; n < 2; ++n) {
                acc[m][n] = __builtin_amdgcn_mfma_f32_16x16x32_f16(ah[m], bh[n], acc[m][n], 0, 0, 0);
                acc[m][n] = __builtin_amdgcn_mfma_f32_16x16x32_f16(ah[m], bl[n], acc[m][n], 0, 0, 0);
                acc[m][n] = __builtin_amdgcn_mfma_f32_16x16x32_f16(al[m], bh[n], acc[m][n], 0, 0, 0);
            }
    }

#pragma unroll
    for (int n = 0; n < 2; ++n) {
        const int col  = n0g + wc * 32 + n * 16 + (lane & 15);
        const float bias = bs[col];
#pragma unroll
        for (int m = 0; m < 4; ++m) {
            const int rbase = row0 + wr * 64 + m * 16 + (lane >> 4) * 4;
#pragma unroll
            for (int reg = 0; reg < 4; ++reg) {
                const float o = gelu_f(acc[m][n][reg] * (1.0f / 1024.0f) + bias);
                h[(size_t)(rbase + reg) * DM + col] = o;
            }
        }
    }
}

// ---------------- W_experts fp32 [e][k][n] -> bf16 transposed [e][n][k] ----------------
__global__ __launch_bounds__(256) void k_wt_bf16(
    const float* __restrict__ We, unsigned short* __restrict__ WeT)
{
    __shared__ float s[32][33];
    const int e  = blockIdx.z;
    const int k0 = blockIdx.y * 32, n0 = blockIdx.x * 32;
    const int c  = threadIdx.x & 31, r = threadIdx.x >> 5;
    const float* W = We + ((size_t)e << 20);
#pragma unroll
    for (int p = 0; p < 4; ++p) {
        const int k = r + p * 8;
        s[k][c] = W[(size_t)(k0 + k) * DM + n0 + c];
    }
    __syncthreads();
#pragma unroll
    for (int p = 0; p < 4; ++p) {
        const int n = r + p * 8;
        WeT[((size_t)e << 20) + (size_t)(n0 + n) * DM + k0 + c] = f2bf(s[c][n]);
    }
}

// ---------------- gate top-2: fp32 exact, NO atomics (scalar-load form, twice-validated) ----------------
__global__ __launch_bounds__(256) void k_gate_topk(
    const float* __restrict__ h, const float* __restrict__ Wg,
    const float* __restrict__ bg, int* __restrict__ eidx,
    float2* __restrict__ w01)
{
    const int lane = threadIdx.x & 63;
    const int wv   = threadIdx.x >> 6;
    const int tok  = blockIdx.x * 4 + wv;
    const float* hr = h + (size_t)tok * DM;
    float acc[NEXP];
#pragma unroll
    for (int e = 0; e < NEXP; ++e) acc[e] = 0.f;
    for (int j = 0; j < DM / 64; ++j) {
        const float hv = hr[lane + 64 * j];
        const float* wr = Wg + (size_t)(lane + 64 * j) * NEXP;
#pragma unroll
        for (int e = 0; e < NEXP; ++e) acc[e] = fmaf(hv, wr[e], acc[e]);
    }
#pragma unroll
    for (int off = 32; off > 0; off >>= 1) {
#pragma unroll
        for (int e = 0; e < NEXP; ++e) acc[e] += __shfl_xor(acc[e], off, 64);
    }
    if (lane == 0) {
        float lg[NEXP];
        float mx = -1e30f;
#pragma unroll
        for (int e = 0; e < NEXP; ++e) { lg[e] = acc[e] + bg[e]; mx = fmaxf(mx, lg[e]); }
        float p[NEXP]; float s = 0.f;
#pragma unroll
        for (int e = 0; e < NEXP; ++e) { p[e] = expf(lg[e] - mx); s += p[e]; }
        const float inv = 1.f / s;
        int i0 = 0;
#pragma unroll
        for (int e = 1; e < NEXP; ++e) if (p[e] > p[i0]) i0 = e;
        int i1 = (i0 == 0) ? 1 : 0;
#pragma unroll
        for (int e = 0; e < NEXP; ++e) if (e != i0 && p[e] > p[i1]) i1 = e;
        eidx[tok] = i0 | (i1 << 8);
        w01[tok]  = make_float2(p[i0] * inv, p[i1] * inv);
    }
}

// ---------------- bucketize: block-aggregated; records per-token slots for 1-read gather ----------------
__global__ __launch_bounds__(256) void k_bucket(
    const int* __restrict__ eidx,
    int* __restrict__ counts, int* __restrict__ btok, int2* __restrict__ tokslot)
{
    __shared__ int lcnt[NEXP], lbase[NEXP];
    const int tid = threadIdx.x;
    const int tok = blockIdx.x * 256 + tid;
    if (tid < NEXP) lcnt[tid] = 0;
    __syncthreads();
    const int ee = eidx[tok];
    const int e0 = ee & 0xff, e1 = ee >> 8;
    const int l0 = atomicAdd(&lcnt[e0], 1);
    const int l1 = atomicAdd(&lcnt[e1], 1);
    __syncthreads();
    if (tid < NEXP) lbase[tid] = atomicAdd(&counts[tid], lcnt[tid]);
    __syncthreads();
    const int s0 = lbase[e0] + l0;
    const int s1 = lbase[e1] + l1;
    btok[e0 * NB_TOK + s0] = tok;            // primary
    btok[e1 * NB_TOK + s1] = tok | SECBIT;   // secondary
    tokslot[tok] = make_int2((e0 << 16) | s0, (e1 << 16) | s1);
}

// ---------------- gather: token-major, ONE h-row read per token -> both compact slots ----------------
__global__ __launch_bounds__(256) void k_gather(
    const float* __restrict__ h, const int2* __restrict__ tokslot,
    const int* __restrict__ counts, unsigned short* __restrict__ hbfc)
{
    const int tok = blockIdx.x;
    const int2 ts = tokslot[tok];
    const int e0 = ts.x >> 16, s0 = ts.x & 0xFFFF;
    const int e1 = ts.y >> 16, s1 = ts.y & 0xFFFF;
    int base0 = 0, base1 = 0, r = 0;
#pragma unroll
    for (int i = 0; i < NEXP; ++i) {
        if (i == e0) base0 = r;
        if (i == e1) base1 = r;
        r += counts[i];
    }
    const int c = threadIdx.x * 4;
    const float4 v = *(const float4*)(h + (size_t)tok * DM + c);
    ushort4v o;
    o[0] = f2bf(v.x); o[1] = f2bf(v.y); o[2] = f2bf(v.z); o[3] = f2bf(v.w);
    *(ushort4v*)(hbfc + (size_t)(base0 + s0) * DM + c) = o;
    *(ushort4v*)(hbfc + (size_t)(base1 + s1) * DM + c) = o;
}

// ---------------- expert GEMM: bf16 MFMA, compacted A, XCD-group swizzle ----------------
// Decode: x=bid&7 (XCD), nt=(bid>>3)&7, gs=bid>>6; group (e,rb)=((x+gs)&7, gs).
#define EXP_STAGE(k0)                                                                                 \
    {                                                                                                 \
        char* lAw = (char*)&ldsA[0][0];                                                               \
        char* lBw = (char*)&ldsB[0][0];                                                               \
        _Pragma("unroll")                                                                             \
        for (int q = 0; q < 4; ++q) {                                                                 \
            __builtin_amdgcn_global_load_lds(AS1U(srcA[q] + (k0)), AS3U(lAw + q * 4096 + wave * 1024), 16, 0, 0); \
            __builtin_amdgcn_global_load_lds(AS1U(srcB[q] + (k0)), AS3U(lBw + q * 4096 + wave * 1024), 16, 0, 0); \
        }                                                                                             \
    }

__global__ __launch_bounds__(256) void k_expert_mfma(
    const unsigned short* __restrict__ hbfc,
    const unsigned short* __restrict__ WeT,
    const float* __restrict__ bexp,
    const int* __restrict__ counts,
    const int* __restrict__ btok,
    float* __restrict__ stage2, float* __restrict__ out)
{
    const int bid = blockIdx.x;
    const int x   = bid & 7;
    const int nt  = (bid >> 3) & 7;
    const int gs  = bid >> 6;            // 0..127
    const int e   = (x + gs) & 7;
    const int rb  = gs;
    int gb = 0, cnt = 0, r_ = 0;
#pragma unroll
    for (int i = 0; i < NEXP; ++i) {
        if (i == e) { gb = r_; cnt = counts[i]; }
        r_ += counts[i];
    }
    const int row0 = rb * 128;
    if (row0 >= cnt) return;

    __shared__ unsigned short ldsA[128][64];   // single-buffered: 33.3KB -> 4 blocks/CU
    __shared__ unsigned short ldsB[128][64];
    __shared__ int sTok[128];

    const int t    = threadIdx.x;
    const int lane = t & 63;
    const int wave = t >> 6;

    const int srow = t >> 3;
    const int g    = (t & 7) ^ (srow & 7);
    const int n0g  = nt * 128;
    const unsigned short* srcA[4];
    const unsigned short* srcB[4];
#pragma unroll
    for (int q = 0; q < 4; ++q) {
        srcA[q] = hbfc + (size_t)(gb + row0 + q * 32 + srow) * DM + g * 8;
        srcB[q] = WeT + ((size_t)e << 20) + (size_t)(n0g + q * 32 + srow) * DM + g * 8;
    }

    EXP_STAGE(0);   // issue tile 0 before sTok loads (independent)

    if (t < 128) {
        const int idx = row0 + t;
        sTok[t] = (idx < cnt) ? btok[e * NB_TOK + idx] : 0;
    }

    const int grp = lane >> 4;
    int offA[2][4], offB[2][4];
#pragma unroll
    for (int ks = 0; ks < 2; ++ks)
#pragma unroll
        for (int m = 0; m < 4; ++m) {
            const int rA = ((wave >> 1) * 64) + m * 16 + (lane & 15);
            const int rB = ((wave & 1) * 64) + m * 16 + (lane & 15);
            const int c  = ks * 4 + grp;
            offA[ks][m] = rA * 128 + (((c ^ (rA & 7)) & 7) << 4);
            offB[ks][m] = rB * 128 + (((c ^ (rB & 7)) & 7) << 4);
        }

    floatx4 acc[4][4];
#pragma unroll
    for (int m = 0; m < 4; ++m)
#pragma unroll
        for (int n = 0; n < 4; ++n) acc[m][n] = (floatx4){0.f, 0.f, 0.f, 0.f};

    const char* lA = (const char*)&ldsA[0][0];
    const char* lB = (const char*)&ldsB[0][0];

    for (int kt = 0; kt < DM / 64; ++kt) {
        __syncthreads();   // tile kt staged & visible
#pragma unroll
        for (int ks = 0; ks < 2; ++ks) {
            short8 av[4], bv[4];
#pragma unroll
            for (int m = 0; m < 4; ++m) av[m] = *(const short8*)(lA + offA[ks][m]);
#pragma unroll
            for (int n = 0; n < 4; ++n) bv[n] = *(const short8*)(lB + offB[ks][n]);
#pragma unroll
            for (int m = 0; m < 4; ++m)
#pragma unroll
                for (int n = 0; n < 4; ++n)
                    acc[m][n] = __builtin_amdgcn_mfma_f32_16x16x32_bf16(av[m], bv[n], acc[m][n], 0, 0, 0);
        }
        if (kt + 1 < DM / 64) {
            __syncthreads();
            EXP_STAGE((kt + 1) * 64);
        }
    }

    // RAW epilogue: store acc+bias only; gelu+weight deferred to k_combine
    const int wr = wave >> 1, wc = wave & 1;
#pragma unroll
    for (int n = 0; n < 4; ++n) {
        const int col  = n0g + wc * 64 + n * 16 + (lane & 15);
        const float bias = bexp[e * DM + col];
#pragma unroll
        for (int m = 0; m < 4; ++m) {
            const int rbase = wr * 64 + m * 16 + (lane >> 4) * 4;
#pragma unroll
            for (int reg = 0; reg < 4; ++reg) {
                const int r = rbase + reg;
                if (row0 + r >= cnt) continue;
                const int raw = sTok[r];
                const int tok = raw & TOKMSK;
                float* dst = (raw & SECBIT) ? stage2 : out;
                dst[(size_t)tok * DM + col] = acc[m][n][reg] + bias;
            }
        }
    }
}

// ---------------- combine: out[tok] = w0*gelu(out[tok]) + w1*gelu(stage2[tok]) ----------------
__global__ __launch_bounds__(256) void k_combine(
    const float* __restrict__ stage2, const float2* __restrict__ w01,
    float* __restrict__ out)
{
    const int tok = blockIdx.x;
    const int c   = threadIdx.x * 4;
    const float2 w = w01[tok];
    const float4 a = *(const float4*)(out    + (size_t)tok * DM + c);
    const float4 b = *(const float4*)(stage2 + (size_t)tok * DM + c);
    float4 o;
    o.x = w.x * gelu_f(a.x) + w.y * gelu_f(b.x);
    o.y = w.x * gelu_f(a.y) + w.y * gelu_f(b.y);
    o.z = w.x * gelu_f(a.z) + w.y * gelu_f(b.z);
    o.w = w.x * gelu_f(a.w) + w.y * gelu_f(b.w);
    *(float4*)(out + (size_t)tok * DM + c) = o;
}

extern "C" void kernel_launch(void* const* d_in, const int* in_sizes, int n_in,
                              void* d_out, int out_size, void* d_ws, size_t ws_size,
                              hipStream_t stream)
{
    const float* f0 = (const float*)d_in[0];
    const float* f1 = (const float*)d_in[1];
    const float* f2 = (const float*)d_in[2];
    const float* Ws = (const float*)d_in[3];
    const float* bs = (const float*)d_in[4];
    const float* Wg = (const float*)d_in[5];
    const float* bg = (const float*)d_in[6];
    const float* We = (const float*)d_in[7];
    const float* be = (const float*)d_in[8];
    float* out = (float*)d_out;

    // ws layout, peak 166MB (round-14/19/20 proven).
    const size_t MB = 1048576ULL;
    char* base = (char*)d_ws;
    unsigned short* Ah    = (unsigned short*)(base);
    unsigned short* Al    = (unsigned short*)(base + 48 * MB);
    unsigned short* BhT   = (unsigned short*)(base + 96 * MB);
    unsigned short* BlT   = (unsigned short*)(base + 99 * MB);
    float*          h     = (float*)(base + 102 * MB);
    unsigned short* WeT   = (unsigned short*)(base + 2 * MB);
    unsigned short* hbfc  = (unsigned short*)(base + 18 * MB);
    float*          stage2= (float*)(base + 82 * MB);
    int*    counts  = (int*)(base);
    int*    btok    = counts + 64;
    int*    eidx    = (int*)(btok + NEXP * NB_TOK);
    float2* w01     = (float2*)(eidx + NB_TOK);
    int2*   tokslot = (int2*)(w01 + NB_TOK);

    k_splitA<<<NB_TOK * (KIN / 4) / 256, 256, 0, stream>>>(f0, f1, f2, Ah, Al);          // 1
    k_splitB<<<dim3(DM / 32, KIN / 32), 256, 0, stream>>>(Ws, BhT, BlT);                 // 2
    k_shared_mfma<<<1024, 512, 0, stream>>>(Ah, Al, BhT, BlT, bs, h);                    // 3

    hipMemsetAsync(counts, 0, 16 * sizeof(int), stream);
    k_gate_topk<<<NB_TOK / 4, 256, 0, stream>>>(h, Wg, bg, eidx, w01);                   // 4
    k_bucket<<<NB_TOK / 256, 256, 0, stream>>>(eidx, counts, btok, tokslot);             // 5
    k_gather<<<NB_TOK, 256, 0, stream>>>(h, tokslot, counts, hbfc);                      // 6

    k_wt_bf16<<<dim3(DM / 32, DM / 32, NEXP), 256, 0, stream>>>(We, WeT);                // 7

    k_expert_mfma<<<8192, 256, 0, stream>>>(                                             // 8
        hbfc, WeT, be, counts, btok, stage2, out);
    k_combine<<<NB_TOK, 256, 0, stream>>>(stage2, w01, out);                             // 9
}

// Round 22
// 391.773 us; speedup vs baseline: 1.3035x; 1.3035x over previous
//
#include <hip/hip_runtime.h>
#include <math.h>

#define NB_TOK 16384
#define DM     1024
#define NEXP   8
#define KIN    1536
#define SECBIT 0x40000000
#define TOKMSK 0x3FFFFFFF

typedef __attribute__((ext_vector_type(8))) short          short8;
typedef __attribute__((ext_vector_type(8))) unsigned short ushort8;
typedef __attribute__((ext_vector_type(4))) unsigned short ushort4v;
typedef __attribute__((ext_vector_type(8))) _Float16       half8;
typedef __attribute__((ext_vector_type(4))) float          floatx4;

#define AS1U(p) ((const __attribute__((address_space(1))) unsigned int*)(p))
#define AS3U(p) ((__attribute__((address_space(3))) unsigned int*)(p))

// fast gelu: A&S 7.1.26 erf approx, |err| <= 1.5e-7. ~14 VALU ops + one hw v_exp.
__device__ __forceinline__ float gelu_f(float x) {
    const float ax = fabsf(x) * 0.70710678118654752440f;
    const float t  = 1.0f / fmaf(0.3275911f, ax, 1.0f);
    float p = fmaf(t, 1.061405429f, -1.453152027f);
    p = fmaf(t, p, 1.421413741f);
    p = fmaf(t, p, -0.284496736f);
    p = fmaf(t, p, 0.254829592f);
    p = p * t;
    const float e = __expf(-ax * ax);
    float erf = fmaf(-p, e, 1.0f);
    erf = copysignf(erf, x);
    return 0.5f * x * (1.0f + erf);
}

__device__ __forceinline__ unsigned short f2bf(float x) {
    unsigned u = __float_as_uint(x);
    u = (u + 0x7FFF + ((u >> 16) & 1)) >> 16;   // RNE
    return (unsigned short)u;
}

__device__ __forceinline__ void split_h16(float x, unsigned short& hi, unsigned short& lo) {
    _Float16 h = (_Float16)x;
    float r = x - (float)h;
    _Float16 l = (_Float16)r;
    hi = *(unsigned short*)&h;
    lo = *(unsigned short*)&l;
}

// ---------------- feature split: concat fp32 -> fp16 hi/lo [tok][KIN], A scaled x4 ----------------
__global__ __launch_bounds__(256) void k_splitA(
    const float* __restrict__ f0, const float* __restrict__ f1,
    const float* __restrict__ f2, unsigned short* __restrict__ Ah,
    unsigned short* __restrict__ Al)
{
    const int i4  = blockIdx.x * 256 + threadIdx.x;
    const int tok = i4 / (KIN / 4);
    const int k   = (i4 % (KIN / 4)) * 4;
    const float* src; int ld, c;
    if (k < 768)       { src = f0; ld = 768; c = k; }
    else if (k < 1280) { src = f1; ld = 512; c = k - 768; }
    else               { src = f2; ld = 256; c = k - 1280; }
    const float4 v = *(const float4*)(src + (size_t)tok * ld + c);
    const float* vp = (const float*)&v;
    ushort4v hi, lo;
#pragma unroll
    for (int j = 0; j < 4; ++j) {
        unsigned short h, l;
        split_h16(vp[j] * 4.0f, h, l);
        hi[j] = h; lo[j] = l;
    }
    *(ushort4v*)(Ah + (size_t)tok * KIN + k) = hi;
    *(ushort4v*)(Al + (size_t)tok * KIN + k) = lo;
}

// ---------------- Ws fp32 [k][n] -> fp16 hi/lo transposed [n][k], scaled x256 ----------------
__global__ __launch_bounds__(256) void k_splitB(
    const float* __restrict__ Ws, unsigned short* __restrict__ BhT,
    unsigned short* __restrict__ BlT)
{
    __shared__ float s[32][33];
    const int n0 = blockIdx.x * 32, k0 = blockIdx.y * 32;
    const int c  = threadIdx.x & 31, r = threadIdx.x >> 5;
#pragma unroll
    for (int p = 0; p < 4; ++p)
        s[r + p * 8][c] = Ws[(size_t)(k0 + r + p * 8) * DM + n0 + c];
    __syncthreads();
#pragma unroll
    for (int p = 0; p < 4; ++p) {
        const int n = r + p * 8;
        unsigned short h, l;
        split_h16(s[c][n] * 256.0f, h, l);
        BhT[(size_t)(n0 + n) * KIN + k0 + c] = h;
        BlT[(size_t)(n0 + n) * KIN + k0 + c] = l;
    }
}

// ---------------- shared GEMM: fp16x2-split MFMA, 512 threads / 8 waves, BK=64 ----------------
__global__ __launch_bounds__(512) void k_shared_mfma(
    const unsigned short* __restrict__ Ah, const unsigned short* __restrict__ Al,
    const unsigned short* __restrict__ BhT, const unsigned short* __restrict__ BlT,
    const float* __restrict__ bs, float* __restrict__ h)
{
    __shared__ unsigned short ldsAh[128][64];
    __shared__ unsigned short ldsAl[128][64];
    __shared__ unsigned short ldsBh[128][64];
    __shared__ unsigned short ldsBl[128][64];

    const int t    = threadIdx.x;          // 0..511
    const int lane = t & 63;
    const int wave = t >> 6;               // 0..7
    const int bid  = blockIdx.x;
    const int brow = ((bid >> 6) << 3) + (bid & 7);   // 0..127
    const int bcol = (bid >> 3) & 7;                  // 0..7
    const int row0 = brow * 128;
    const int n0g  = bcol * 128;

    const int srow = t >> 3;               // 0..63
    const int g    = (t & 7) ^ (srow & 7);
    const unsigned short *sAh[2], *sAl[2], *sBh[2], *sBl[2];
#pragma unroll
    for (int q = 0; q < 2; ++q) {
        const size_t ra = (size_t)(row0 + q * 64 + srow) * KIN + g * 8;
        const size_t rb = (size_t)(n0g + q * 64 + srow) * KIN + g * 8;
        sAh[q] = Ah + ra; sAl[q] = Al + ra;
        sBh[q] = BhT + rb; sBl[q] = BlT + rb;
    }

    const int grp = lane >> 4;
    const int wr = wave >> 2, wc = wave & 3;
    int offA[2][4], offB[2][2];
#pragma unroll
    for (int ks = 0; ks < 2; ++ks) {
#pragma unroll
        for (int m = 0; m < 4; ++m) {
            const int rA = wr * 64 + m * 16 + (lane & 15);
            const int c  = ks * 4 + grp;
            offA[ks][m] = rA * 128 + (((c ^ (rA & 7)) & 7) << 4);
        }
#pragma unroll
        for (int n = 0; n < 2; ++n) {
            const int rB = wc * 32 + n * 16 + (lane & 15);
            const int c  = ks * 4 + grp;
            offB[ks][n] = rB * 128 + (((c ^ (rB & 7)) & 7) << 4);
        }
    }

    floatx4 acc[4][2];
#pragma unroll
    for (int m = 0; m < 4; ++m)
#pragma unroll
        for (int n = 0; n < 2; ++n) acc[m][n] = (floatx4){0.f, 0.f, 0.f, 0.f};

    const char* lAh = (const char*)&ldsAh[0][0];
    const char* lAl = (const char*)&ldsAl[0][0];
    const char* lBh = (const char*)&ldsBh[0][0];
    const char* lBl = (const char*)&ldsBl[0][0];

    for (int kt = 0; kt < KIN / 64; ++kt) {
        const int k0 = kt * 64;
        __syncthreads();
#pragma unroll
        for (int q = 0; q < 2; ++q) {
            const int dst = q * 8192 + t * 16;
            __builtin_amdgcn_global_load_lds(AS1U(sAh[q] + k0), AS3U((char*)lAh + dst), 16, 0, 0);
            __builtin_amdgcn_global_load_lds(AS1U(sAl[q] + k0), AS3U((char*)lAl + dst), 16, 0, 0);
            __builtin_amdgcn_global_load_lds(AS1U(sBh[q] + k0), AS3U((char*)lBh + dst), 16, 0, 0);
            __builtin_amdgcn_global_load_lds(AS1U(sBl[q] + k0), AS3U((char*)lBl + dst), 16, 0, 0);
        }
        __syncthreads();
#pragma unroll
        for (int ks = 0; ks < 2; ++ks) {
            half8 ah[4], al[4], bh[2], bl[2];
#pragma unroll
            for (int m = 0; m < 4; ++m) {
                ah[m] = *(const half8*)(lAh + offA[ks][m]);
                al[m] = *(const half8*)(lAl + offA[ks][m]);
            }
#pragma unroll
            for (int n = 0; n < 2; ++n) {
                bh[n] = *(const half8*)(lBh + offB[ks][n]);
                bl[n] = *(const half8*)(lBl + offB[ks][n]);
            }
#pragma unroll
            for (int m = 0; m < 4; ++m)
#pragma unroll
                for (int n = 0; n < 2; ++n) {
                    acc[m][n] = __builtin_amdgcn_mfma_f32_16x16x32_f16(ah[m], bh[n], acc[m][n], 0, 0, 0);
                    acc[m][n] = __builtin_amdgcn_mfma_f32_16x16x32_f16(ah[m], bl[n], acc[m][n], 0, 0, 0);
                    acc[m][n] = __builtin_amdgcn_mfma_f32_16x16x32_f16(al[m], bh[n], acc[m][n], 0, 0, 0);
                }
        }
    }

#pragma unroll
    for (int n = 0; n < 2; ++n) {
        const int col  = n0g + wc * 32 + n * 16 + (lane & 15);
        const float bias = bs[col];
#pragma unroll
        for (int m = 0; m < 4; ++m) {
            const int rbase = row0 + wr * 64 + m * 16 + (lane >> 4) * 4;
#pragma unroll
            for (int reg = 0; reg < 4; ++reg) {
                const float o = gelu_f(acc[m][n][reg] * (1.0f / 1024.0f) + bias);
                h[(size_t)(rbase + reg) * DM + col] = o;
            }
        }
    }
}

// ---------------- W_experts fp32 [e][k][n] -> bf16 transposed [e][n][k] ----------------
__global__ __launch_bounds__(256) void k_wt_bf16(
    const float* __restrict__ We, unsigned short* __restrict__ WeT)
{
    __shared__ float s[32][33];
    const int e  = blockIdx.z;
    const int k0 = blockIdx.y * 32, n0 = blockIdx.x * 32;
    const int c  = threadIdx.x & 31, r = threadIdx.x >> 5;
    const float* W = We + ((size_t)e << 20);
#pragma unroll
    for (int p = 0; p < 4; ++p) {
        const int k = r + p * 8;
        s[k][c] = W[(size_t)(k0 + k) * DM + n0 + c];
    }
    __syncthreads();
#pragma unroll
    for (int p = 0; p < 4; ++p) {
        const int n = r + p * 8;
        WeT[((size_t)e << 20) + (size_t)(n0 + n) * DM + k0 + c] = f2bf(s[c][n]);
    }
}

// ---------------- gate top-2: fp32 exact, NO atomics (scalar-load form, twice-validated) ----------------
__global__ __launch_bounds__(256) void k_gate_topk(
    const float* __restrict__ h, const float* __restrict__ Wg,
    const float* __restrict__ bg, int* __restrict__ eidx,
    float2* __restrict__ w01)
{
    const int lane = threadIdx.x & 63;
    const int wv   = threadIdx.x >> 6;
    const int tok  = blockIdx.x * 4 + wv;
    const float* hr = h + (size_t)tok * DM;
    float acc[NEXP];
#pragma unroll
    for (int e = 0; e < NEXP; ++e) acc[e] = 0.f;
    for (int j = 0; j < DM / 64; ++j) {
        const float hv = hr[lane + 64 * j];
        const float* wr = Wg + (size_t)(lane + 64 * j) * NEXP;
#pragma unroll
        for (int e = 0; e < NEXP; ++e) acc[e] = fmaf(hv, wr[e], acc[e]);
    }
#pragma unroll
    for (int off = 32; off > 0; off >>= 1) {
#pragma unroll
        for (int e = 0; e < NEXP; ++e) acc[e] += __shfl_xor(acc[e], off, 64);
    }
    if (lane == 0) {
        float lg[NEXP];
        float mx = -1e30f;
#pragma unroll
        for (int e = 0; e < NEXP; ++e) { lg[e] = acc[e] + bg[e]; mx = fmaxf(mx, lg[e]); }
        float p[NEXP]; float s = 0.f;
#pragma unroll
        for (int e = 0; e < NEXP; ++e) { p[e] = expf(lg[e] - mx); s += p[e]; }
        const float inv = 1.f / s;
        int i0 = 0;
#pragma unroll
        for (int e = 1; e < NEXP; ++e) if (p[e] > p[i0]) i0 = e;
        int i1 = (i0 == 0) ? 1 : 0;
#pragma unroll
        for (int e = 0; e < NEXP; ++e) if (e != i0 && p[e] > p[i1]) i1 = e;
        eidx[tok] = i0 | (i1 << 8);
        w01[tok]  = make_float2(p[i0] * inv, p[i1] * inv);
    }
}

// ---------------- bucketize: block-aggregated; records per-token slots for 1-read gather ----------------
__global__ __launch_bounds__(256) void k_bucket(
    const int* __restrict__ eidx,
    int* __restrict__ counts, int* __restrict__ btok, int2* __restrict__ tokslot)
{
    __shared__ int lcnt[NEXP], lbase[NEXP];
    const int tid = threadIdx.x;
    const int tok = blockIdx.x * 256 + tid;
    if (tid < NEXP) lcnt[tid] = 0;
    __syncthreads();
    const int ee = eidx[tok];
    const int e0 = ee & 0xff, e1 = ee >> 8;
    const int l0 = atomicAdd(&lcnt[e0], 1);
    const int l1 = atomicAdd(&lcnt[e1], 1);
    __syncthreads();
    if (tid < NEXP) lbase[tid] = atomicAdd(&counts[tid], lcnt[tid]);
    __syncthreads();
    const int s0 = lbase[e0] + l0;
    const int s1 = lbase[e1] + l1;
    btok[e0 * NB_TOK + s0] = tok;            // primary
    btok[e1 * NB_TOK + s1] = tok | SECBIT;   // secondary
    tokslot[tok] = make_int2((e0 << 16) | s0, (e1 << 16) | s1);
}

// ---------------- gather: token-major, ONE h-row read per token -> both compact slots ----------------
__global__ __launch_bounds__(256) void k_gather(
    const float* __restrict__ h, const int2* __restrict__ tokslot,
    const int* __restrict__ counts, unsigned short* __restrict__ hbfc)
{
    const int tok = blockIdx.x;
    const int2 ts = tokslot[tok];
    const int e0 = ts.x >> 16, s0 = ts.x & 0xFFFF;
    const int e1 = ts.y >> 16, s1 = ts.y & 0xFFFF;
    int base0 = 0, base1 = 0, r = 0;
#pragma unroll
    for (int i = 0; i < NEXP; ++i) {
        if (i == e0) base0 = r;
        if (i == e1) base1 = r;
        r += counts[i];
    }
    const int c = threadIdx.x * 4;
    const float4 v = *(const float4*)(h + (size_t)tok * DM + c);
    ushort4v o;
    o[0] = f2bf(v.x); o[1] = f2bf(v.y); o[2] = f2bf(v.z); o[3] = f2bf(v.w);
    *(ushort4v*)(hbfc + (size_t)(base0 + s0) * DM + c) = o;
    *(ushort4v*)(hbfc + (size_t)(base1 + s1) * DM + c) = o;
}

// ---------------- expert GEMM: bf16 MFMA, compacted A, XCD-group swizzle ----------------
// Decode: x=bid&7 (XCD), nt=(bid>>3)&7, gs=bid>>6; group (e,rb)=((x+gs)&7, gs).
#define EXP_STAGE(k0)                                                                                 \
    {                                                                                                 \
        char* lAw = (char*)&ldsA[0][0];                                                               \
        char* lBw = (char*)&ldsB[0][0];                                                               \
        _Pragma("unroll")                                                                             \
        for (int q = 0; q < 4; ++q) {                                                                 \
            __builtin_amdgcn_global_load_lds(AS1U(srcA[q] + (k0)), AS3U(lAw + q * 4096 + wave * 1024), 16, 0, 0); \
            __builtin_amdgcn_global_load_lds(AS1U(srcB[q] + (k0)), AS3U(lBw + q * 4096 + wave * 1024), 16, 0, 0); \
        }                                                                                             \
    }

__global__ __launch_bounds__(256) void k_expert_mfma(
    const unsigned short* __restrict__ hbfc,
    const unsigned short* __restrict__ WeT,
    const float* __restrict__ bexp,
    const int* __restrict__ counts,
    const int* __restrict__ btok,
    float* __restrict__ stage2, float* __restrict__ out)
{
    const int bid = blockIdx.x;
    const int x   = bid & 7;
    const int nt  = (bid >> 3) & 7;
    const int gs  = bid >> 6;            // 0..127
    const int e   = (x + gs) & 7;
    const int rb  = gs;
    int gb = 0, cnt = 0, r_ = 0;
#pragma unroll
    for (int i = 0; i < NEXP; ++i) {
        if (i == e) { gb = r_; cnt = counts[i]; }
        r_ += counts[i];
    }
    const int row0 = rb * 128;
    if (row0 >= cnt) return;

    __shared__ unsigned short ldsA[128][64];   // single-buffered: 33.3KB -> 4 blocks/CU
    __shared__ unsigned short ldsB[128][64];
    __shared__ int sTok[128];

    const int t    = threadIdx.x;
    const int lane = t & 63;
    const int wave = t >> 6;

    const int srow = t >> 3;
    const int g    = (t & 7) ^ (srow & 7);
    const int n0g  = nt * 128;
    const unsigned short* srcA[4];
    const unsigned short* srcB[4];
#pragma unroll
    for (int q = 0; q < 4; ++q) {
        srcA[q] = hbfc + (size_t)(gb + row0 + q * 32 + srow) * DM + g * 8;
        srcB[q] = WeT + ((size_t)e << 20) + (size_t)(n0g + q * 32 + srow) * DM + g * 8;
    }

    EXP_STAGE(0);   // issue tile 0 before sTok loads (independent)

    if (t < 128) {
        const int idx = row0 + t;
        sTok[t] = (idx < cnt) ? btok[e * NB_TOK + idx] : 0;
    }

    const int grp = lane >> 4;
    int offA[2][4], offB[2][4];
#pragma unroll
    for (int ks = 0; ks < 2; ++ks)
#pragma unroll
        for (int m = 0; m < 4; ++m) {
            const int rA = ((wave >> 1) * 64) + m * 16 + (lane & 15);
            const int rB = ((wave & 1) * 64) + m * 16 + (lane & 15);
            const int c  = ks * 4 + grp;
            offA[ks][m] = rA * 128 + (((c ^ (rA & 7)) & 7) << 4);
            offB[ks][m] = rB * 128 + (((c ^ (rB & 7)) & 7) << 4);
        }

    floatx4 acc[4][4];
#pragma unroll
    for (int m = 0; m < 4; ++m)
#pragma unroll
        for (int n = 0; n < 4; ++n) acc[m][n] = (floatx4){0.f, 0.f, 0.f, 0.f};

    const char* lA = (const char*)&ldsA[0][0];
    const char* lB = (const char*)&ldsB[0][0];

    for (int kt = 0; kt < DM / 64; ++kt) {
        __syncthreads();   // tile kt staged & visible
#pragma unroll
        for (int ks = 0; ks < 2; ++ks) {
            short8 av[4], bv[4];
#pragma unroll
            for (int m = 0; m < 4; ++m) av[m] = *(const short8*)(lA + offA[ks][m]);
#pragma unroll
            for (int n = 0; n < 4; ++n) bv[n] = *(const short8*)(lB + offB[ks][n]);
#pragma unroll
            for (int m = 0; m < 4; ++m)
#pragma unroll
                for (int n = 0; n < 4; ++n)
                    acc[m][n] = __builtin_amdgcn_mfma_f32_16x16x32_bf16(av[m], bv[n], acc[m][n], 0, 0, 0);
        }
        if (kt + 1 < DM / 64) {
            __syncthreads();
            EXP_STAGE((kt + 1) * 64);
        }
    }

    // RAW epilogue: store acc+bias only; gelu+weight deferred to k_combine
    const int wr = wave >> 1, wc = wave & 1;
#pragma unroll
    for (int n = 0; n < 4; ++n) {
        const int col  = n0g + wc * 64 + n * 16 + (lane & 15);
        const float bias = bexp[e * DM + col];
#pragma unroll
        for (int m = 0; m < 4; ++m) {
            const int rbase = wr * 64 + m * 16 + (lane >> 4) * 4;
#pragma unroll
            for (int reg = 0; reg < 4; ++reg) {
                const int r = rbase + reg;
                if (row0 + r >= cnt) continue;
                const int raw = sTok[r];
                const int tok = raw & TOKMSK;
                float* dst = (raw & SECBIT) ? stage2 : out;
                dst[(size_t)tok * DM + col] = acc[m][n][reg] + bias;
            }
        }
    }
}

// ---------------- combine: out[tok] = w0*gelu(out[tok]) + w1*gelu(stage2[tok]) ----------------
__global__ __launch_bounds__(256) void k_combine(
    const float* __restrict__ stage2, const float2* __restrict__ w01,
    float* __restrict__ out)
{
    const int tok = blockIdx.x;
    const int c   = threadIdx.x * 4;
    const float2 w = w01[tok];
    const float4 a = *(const float4*)(out    + (size_t)tok * DM + c);
    const float4 b = *(const float4*)(stage2 + (size_t)tok * DM + c);
    float4 o;
    o.x = w.x * gelu_f(a.x) + w.y * gelu_f(b.x);
    o.y = w.x * gelu_f(a.y) + w.y * gelu_f(b.y);
    o.z = w.x * gelu_f(a.z) + w.y * gelu_f(b.z);
    o.w = w.x * gelu_f(a.w) + w.y * gelu_f(b.w);
    *(float4*)(out + (size_t)tok * DM + c) = o;
}

extern "C" void kernel_launch(void* const* d_in, const int* in_sizes, int n_in,
                              void* d_out, int out_size, void* d_ws, size_t ws_size,
                              hipStream_t stream)
{
    const float* f0 = (const float*)d_in[0];
    const float* f1 = (const float*)d_in[1];
    const float* f2 = (const float*)d_in[2];
    const float* Ws = (const float*)d_in[3];
    const float* bs = (const float*)d_in[4];
    const float* Wg = (const float*)d_in[5];
    const float* bg = (const float*)d_in[6];
    const float* We = (const float*)d_in[7];
    const float* be = (const float*)d_in[8];
    float* out = (float*)d_out;

    // ws layout, peak 166MB (round-14/19/20 proven).
    const size_t MB = 1048576ULL;
    char* base = (char*)d_ws;
    unsigned short* Ah    = (unsigned short*)(base);
    unsigned short* Al    = (unsigned short*)(base + 48 * MB);
    unsigned short* BhT   = (unsigned short*)(base + 96 * MB);
    unsigned short* BlT   = (unsigned short*)(base + 99 * MB);
    float*          h     = (float*)(base + 102 * MB);
    unsigned short* WeT   = (unsigned short*)(base + 2 * MB);
    unsigned short* hbfc  = (unsigned short*)(base + 18 * MB);
    float*          stage2= (float*)(base + 82 * MB);
    int*    counts  = (int*)(base);
    int*    btok    = counts + 64;
    int*    eidx    = (int*)(btok + NEXP * NB_TOK);
    float2* w01     = (float2*)(eidx + NB_TOK);
    int2*   tokslot = (int2*)(w01 + NB_TOK);

    k_splitA<<<NB_TOK * (KIN / 4) / 256, 256, 0, stream>>>(f0, f1, f2, Ah, Al);          // 1
    k_splitB<<<dim3(DM / 32, KIN / 32), 256, 0, stream>>>(Ws, BhT, BlT);                 // 2
    k_shared_mfma<<<1024, 512, 0, stream>>>(Ah, Al, BhT, BlT, bs, h);                    // 3

    hipMemsetAsync(counts, 0, 16 * sizeof(int), stream);
    k_gate_topk<<<NB_TOK / 4, 256, 0, stream>>>(h, Wg, bg, eidx, w01);                   // 4
    k_bucket<<<NB_TOK / 256, 256, 0, stream>>>(eidx, counts, btok, tokslot);             // 5
    k_gather<<<NB_TOK, 256, 0, stream>>>(h, tokslot, counts, hbfc);                      // 6

    k_wt_bf16<<<dim3(DM / 32, DM / 32, NEXP), 256, 0, stream>>>(We, WeT);                // 7

    k_expert_mfma<<<8192, 256, 0, stream>>>(                                             // 8
        hbfc, WeT, be, counts, btok, stage2, out);
    k_combine<<<NB_TOK, 256, 0, stream>>>(stage2, w01, out);                             // 9
}